// Round 14
// baseline (3105.256 us; speedup 1.0000x reference)
//
#include <hip/hip_runtime.h>
#include <hip/hip_bf16.h>
#include <math.h>

#define TS   256
#define CTS  512
#define MB   64
#define D    512
#define KMIX 20

// d_out layout (floats): hiddens [TS][MB][D], att_k [TS][MB][KMIX], att_w [TS][MB][D]
#define HID_SIZE  (TS*MB*D)
#define ATTK_OFF  (HID_SIZE)
#define ATTW_OFF  (HID_SIZE + TS*MB*KMIX)

// ws layout (bytes):
#define WS_WRPK8 0            // 256KB  i8 packed reset-Wur
#define WS_UPK8  262144       // 256KB  i8 packed U
#define WS_WSC   524288       // 4KB    wscWr[512], wscU[512]
#define WS_BIAS1 528384       // 2KB    biasR1[512]
#define WS_BIAS2 530432       // 4KB    biasR2[1024]
#define WS_ALPHA 1048576
#define WS_BETA  2359296
#define WS_KINC  3670016
#define WS_X     5242880      // XB bf16 [16384][512] = 16MB
#define WS_F2T   (5242880 + 16777216)   // F2T bf16 16MB; ALSO hosts WIFPK/WFORKPK early (dead before pack_f2t)
#define WS_WIFPK   WS_F2T               // 512KB, dead before F2T written
#define WS_WFORKPK (WS_F2T + 524288)    // 1MB, dead after gemm2
#define WS_F2    38797312     // F2B bf16 [16384][1024] = 32MB

typedef __attribute__((ext_vector_type(2))) long long ll2;
typedef __attribute__((ext_vector_type(4))) int i32x4;
typedef __attribute__((ext_vector_type(8))) short bf16x8;
typedef __attribute__((ext_vector_type(4))) float f32x4;
typedef __attribute__((ext_vector_type(8))) unsigned short ushort8;

__device__ __forceinline__ unsigned short f2bf(float v) {
  __hip_bfloat16 h = __float2bfloat16(v);
  union { __hip_bfloat16 h; unsigned short u; } cvt; cvt.h = h;
  return cvt.u;
}
__device__ __forceinline__ float bf2f(unsigned short u) {
  return __uint_as_float(((unsigned)u) << 16);
}

// ---------------- K0a: per-output-column weight scales (recurrence i8) ----------------
__global__ __launch_bounds__(256) void col_scales(const float* __restrict__ Wur,
                                                  const float* __restrict__ U,
                                                  float* __restrict__ wscWr,
                                                  float* __restrict__ wscU) {
  int j = blockIdx.x * 256 + threadIdx.x;
  if (j >= 512) return;
  float mw = 0.f, mu = 0.f;
  for (int k = 0; k < 512; k++) {
    mw = fmaxf(mw, fabsf(Wur[k * 1024 + 512 + j]));
    mu = fmaxf(mu, fabsf(U[k * 512 + j]));
  }
  wscWr[j] = fmaxf(mw, 1e-20f) * (1.0f / 127.0f);
  wscU[j]  = fmaxf(mu, 1e-20f) * (1.0f / 127.0f);
}

// ---------------- K0b: pack recurrence weights to i8, pair-interleaved B-frag layout ----
__global__ __launch_bounds__(256) void pack_weights_i8(const float* __restrict__ Wur,
                                                       const float* __restrict__ U,
                                                       const float* __restrict__ wscWr,
                                                       const float* __restrict__ wscU,
                                                       signed char* __restrict__ WrPK8,
                                                       signed char* __restrict__ UPK8) {
  int o = blockIdx.x * 256 + threadIdx.x;   // 0..262143
  int e = o & 7, half = (o >> 3) & 1, l = (o >> 4) & 63, p = (o >> 10) & 7, nt = o >> 13;
  int k = (2 * p + half) * 32 + ((l >> 4) & 3) * 8 + e;
  int n = nt * 16 + (l & 15);
  float i1 = __builtin_amdgcn_rcpf(wscWr[n]);
  float i2 = __builtin_amdgcn_rcpf(wscU[n]);
  int q1 = __float2int_rn(Wur[k * 1024 + 512 + n] * i1);
  int q2 = __float2int_rn(U[k * 512 + n] * i2);
  q1 = q1 > 127 ? 127 : (q1 < -127 ? -127 : q1);
  q2 = q2 > 127 ? 127 : (q2 < -127 ? -127 : q2);
  WrPK8[o] = (signed char)q1;
  UPK8[o]  = (signed char)q2;
}

// ---------------- K0c: pack GEMM weights to bf16 B-frag layout (+remapped bias) ----------
__global__ __launch_bounds__(256) void pack_gemm_w(const float* __restrict__ W,
                                                   const float* __restrict__ bias,
                                                   unsigned short* __restrict__ out,
                                                   float* __restrict__ biasR,
                                                   int ldw, int N, int remap) {
  int idx = blockIdx.x * 256 + threadIdx.x;   // N*512 total
  int e = idx & 7, l = (idx >> 3) & 63, f = idx >> 9;
  int kt = f & 15, nt = f >> 4;
  int k = kt * 32 + ((l >> 4) << 3) + e;
  int n = (nt << 4) + (l & 15);
  int col = (remap && n >= 512) ? n + 512 : n;
  out[idx] = f2bf(W[(size_t)k * ldw + col]);
  if (idx < N) biasR[idx] = bias[(remap && idx >= 512) ? idx + 512 : idx];
}

// ---------------- K1: alpha = inp@Wa+ba (log domain), beta, kinc ----------------
#define ABK_ROWS 8
__global__ __launch_bounds__(64) void abk_kernel(const float* __restrict__ inp,
                                                 const float* __restrict__ Wa, const float* __restrict__ ba,
                                                 const float* __restrict__ Wb, const float* __restrict__ bb_,
                                                 const float* __restrict__ Wk, const float* __restrict__ bk,
                                                 float* __restrict__ alpha, float* __restrict__ beta,
                                                 float* __restrict__ kinc) {
  __shared__ float rows[ABK_ROWS][D];
  int tb0 = blockIdx.x * ABK_ROWS;
  for (int x = threadIdx.x; x < ABK_ROWS * D; x += 64)
    rows[x >> 9][x & 511] = inp[(size_t)tb0 * D + x];
  __syncthreads();
  int j = threadIdx.x;
  if (j >= 3 * KMIX) return;
  int wj = j % KMIX;
  int which = j / KMIX;
  const float* W = (which == 0) ? Wa : ((which == 1) ? Wb : Wk);
  const float* B = (which == 0) ? ba : ((which == 1) ? bb_ : bk);
  float acc[ABK_ROWS];
  float bias = B[wj];
#pragma unroll
  for (int r = 0; r < ABK_ROWS; r++) acc[r] = bias;
  for (int i = 0; i < D; i++) {
    float wv = W[i * KMIX + wj];
#pragma unroll
    for (int r = 0; r < ABK_ROWS; r++) acc[r] += rows[r][i] * wv;
  }
  for (int r = 0; r < ABK_ROWS; r++) {
    int tb = tb0 + r;
    float v = acc[r];
    if (which == 0) alpha[tb * KMIX + wj] = v;
    else if (which == 1) beta[tb * KMIX + wj] = expf(v);
    else kinc[tb * KMIX + wj] = expf(v);
  }
}

// ---------------- K2: k cumsum over t; writes att_k region of d_out ----------------
__global__ __launch_bounds__(256) void cumsum_kernel(const float* __restrict__ att_init,
                                                     const float* __restrict__ kinc,
                                                     float* __restrict__ kout) {
  int idx = blockIdx.x * 256 + threadIdx.x;
  if (idx >= MB * KMIX) return;
  float k = att_init[idx];
  for (int t = 0; t < TS; t++) {
    k += kinc[t * MB * KMIX + idx];
    kout[t * MB * KMIX + idx] = k;
  }
}

// ---------------- K3: phi + w GEMM; writes att_w region of d_out ----------------
// WT=32 (round 14): halves the c_inp L3 re-read (1GB -> 0.5GB). LDS ~71.5KB, 2 blocks/CU.
#define WT 32
__global__ __launch_bounds__(512) void phi_w_kernel(const float* __restrict__ c_inp,
                                                    const float* __restrict__ alpha,
                                                    const float* __restrict__ beta,
                                                    const float* __restrict__ katt,
                                                    float* __restrict__ wout) {
  int b  = blockIdx.x / (TS / WT);
  int t0 = (blockIdx.x % (TS / WT)) * WT;
  __shared__ float phi[WT][CTS];
  __shared__ float pa[WT][KMIX], pb[WT][KMIX], pk[WT][KMIX];
  for (int x = threadIdx.x; x < WT * KMIX; x += 512) {
    int tt = x / KMIX, j = x % KMIX;
    int tb = (t0 + tt) * MB + b;
    pa[tt][j] = alpha[tb * KMIX + j];
    pb[tt][j] = beta[tb * KMIX + j];
    pk[tt][j] = katt[tb * KMIX + j];
  }
  __syncthreads();
  {
    int c = threadIdx.x;
    float fc = (float)c;
#pragma unroll
    for (int tt = 0; tt < WT; tt++) {
      float s = 0.f;
#pragma unroll
      for (int j = 0; j < KMIX; j++) {
        float dd = pk[tt][j] - fc;
        s += expf(pa[tt][j] - pb[tt][j] * dd * dd);
      }
      phi[tt][c] = s;
    }
  }
  __syncthreads();
  {
    int d = threadIdx.x;
    float acc[WT];
#pragma unroll
    for (int tt = 0; tt < WT; tt++) acc[tt] = 0.f;
    const float* cb = c_inp + (size_t)b * D + d;
    for (int c2 = 0; c2 < CTS; c2++) {
      float cv = cb[(size_t)c2 * (MB * D)];
#pragma unroll
      for (int tt = 0; tt < WT; tt++) acc[tt] += phi[tt][c2] * cv;
    }
    for (int tt = 0; tt < WT; tt++)
      wout[((size_t)(t0 + tt) * MB + b) * D + d] = acc[tt];
  }
}

// ---------------- K4/K5: bf16 MFMA GEMM, 64x128 tile, 8 waves ----------------
// AF32=1,OUTBF=1,Nout=512 : X = inp@Wif + bif + attw -> bf16 XB.
// AF32=0,OUTBF=1,Nout=1024: F2B = XB@WforkR + bforkR -> bf16 [row][1024].
template<int AF32, int OUTBF>
__global__ __launch_bounds__(512) void gemm_mfma(const void* __restrict__ Av,
                                                 const unsigned short* __restrict__ BPK,
                                                 const float* __restrict__ biasR,
                                                 const float* __restrict__ wadd,
                                                 void* __restrict__ Cv, int Nout) {
  __shared__ unsigned short abf[4][16 * 512];   // 64KB
  const int tid = threadIdx.x, wave = tid >> 6, lane = tid & 63;
  const int lg = lane >> 4, ln = lane & 15;
  const int wm = wave & 3, wn = wave >> 2;
  const int m0 = blockIdx.x * 64, n0 = blockIdx.y * 128;
  const int Lsrd = lane ^ ((lane >> 3) & 7);

#pragma unroll
  for (int i = 0; i < 8; i++) {
    int g = (i * 512 + tid) * 8;
    int row = g >> 9, col = g & 511;
    ushort8 u;
    if (AF32) {
      const float* A = (const float*)Av;
      float4 v0 = *(const float4*)(A + (size_t)(m0 + row) * 512 + col);
      float4 v1 = *(const float4*)(A + (size_t)(m0 + row) * 512 + col + 4);
      u[0] = f2bf(v0.x); u[1] = f2bf(v0.y); u[2] = f2bf(v0.z); u[3] = f2bf(v0.w);
      u[4] = f2bf(v1.x); u[5] = f2bf(v1.y); u[6] = f2bf(v1.z); u[7] = f2bf(v1.w);
    } else {
      const unsigned short* A = (const unsigned short*)Av;
      u = *(const ushort8*)(A + (size_t)(m0 + row) * 512 + col);
    }
    int strip = row >> 4, m = row & 15;
    int L = (((col >> 3) & 3) << 4) | m;
    int Ls = L ^ ((L >> 3) & 7);
    *(ushort8*)(&abf[strip][((col >> 5) << 9) + (Ls << 3)]) = u;
  }
  __syncthreads();

  const f32x4 zero4 = {0.f, 0.f, 0.f, 0.f};
  f32x4 acc[4] = {zero4, zero4, zero4, zero4};
  const bf16x8* BP = (const bf16x8*)BPK;
  const int ntbase = (n0 >> 4) + wn * 4;
#pragma unroll
  for (int kt = 0; kt < 16; kt++) {
    bf16x8 a = *(const bf16x8*)(&abf[wm][(kt << 9) + (Lsrd << 3)]);
#pragma unroll
    for (int q = 0; q < 4; q++)
      acc[q] = __builtin_amdgcn_mfma_f32_16x16x32_bf16(
          a, BP[(((ntbase + q) * 16 + kt) << 6) + lane], acc[q], 0, 0, 0);
  }

#pragma unroll
  for (int q = 0; q < 4; q++) {
    int col = n0 + ((wn * 4 + q) << 4) + ln;
    float bb = biasR[col];
#pragma unroll
    for (int r = 0; r < 4; r++) {
      int row = m0 + (wm << 4) + (lg << 2) + r;
      float v = acc[q][r] + bb;
      if (wadd) v += wadd[(size_t)row * 512 + col];
      if (OUTBF) ((unsigned short*)Cv)[(size_t)row * Nout + col] = f2bf(v);
      else       ((float*)Cv)[(size_t)row * Nout + col] = v;
    }
  }
}

// ---------------- K5b: transpose+pack F2B (bf16) -> F2T bf16 [t][j<512][m][2(s,g)] ------
__global__ __launch_bounds__(256) void pack_f2t(const unsigned short* __restrict__ F2B,
                                                unsigned short* __restrict__ F2T) {
  __shared__ unsigned short ts_[64][66], tg_[64][66];
  int t = blockIdx.x >> 3, jb = (blockIdx.x & 7) << 6;
  const unsigned short* src = F2B + (size_t)t * 64 * 1024;
  for (int mm = 0; mm < 64; mm += 4) {
    int m = mm + (threadIdx.x >> 6);
    int c = threadIdx.x & 63;
    ts_[m][c] = src[(size_t)m * 1024 + jb + c];
    tg_[m][c] = src[(size_t)m * 1024 + 512 + jb + c];
  }
  __syncthreads();
  unsigned short* dst = F2T + ((size_t)t * 512 + jb) * 128;
  for (int base = threadIdx.x; base < 64 * 128; base += 256) {
    int j = base >> 7, idx = base & 127, m = idx >> 1, sel = idx & 1;
    dst[(size_t)j * 128 + idx] = sel ? tg_[m][j] : ts_[m][j];
  }
}

// ---------------- K6: i8 MFMA recurrence, 1024 thr (round-11 verbatim, measured 2500us) ----
__device__ __forceinline__ int a8off(int m, int j) {
  return ((j >> 6) << 10) + (((((j >> 3) & 3) << 4) + m) << 4) + (((j >> 5) & 1) << 3) + (j & 7);
}
__device__ __forceinline__ float fast_sigmoid(float x) {
  return __builtin_amdgcn_rcpf(1.f + __expf(-x));
}
__device__ __forceinline__ float fast_tanh(float x) {
  x = fminf(15.f, fmaxf(-15.f, x));
  float e = __expf(2.f * x);
  return 1.f - 2.f * __builtin_amdgcn_rcpf(e + 1.f);
}

__global__ __launch_bounds__(1024) void recurrence_i8(
    const unsigned short* __restrict__ F2T,
    const signed char* __restrict__ WrPK8,
    const signed char* __restrict__ UPK8,
    const float* __restrict__ wscWr,
    const float* __restrict__ wscU,
    const float* __restrict__ gru_init,
    float* __restrict__ hout) {
  __shared__ long long hq8[1024];    // 8KB i8 A-buffer (h)
  __shared__ long long srq8[1024];   // 8KB i8 A-buffer (sr)
  signed char* hqc  = (signed char*)hq8;
  signed char* srqc = (signed char*)srq8;
  const int tid  = threadIdx.x;
  const int wave = tid >> 6;        // 0..15
  const int lane = tid & 63;
  const int lg = lane >> 4;
  const int ln = lane & 15;
  const int b0 = blockIdx.x * 16;

  const signed char* wrq0 = WrPK8 + (size_t)(wave * 2 + 0) * 8192 + lane * 16;
  const signed char* wrq1 = WrPK8 + (size_t)(wave * 2 + 1) * 8192 + lane * 16;
  const signed char* uq0  = UPK8  + (size_t)(wave * 2 + 0) * 8192 + lane * 16;
  const signed char* uq1  = UPK8  + (size_t)(wave * 2 + 1) * 8192 + lane * 16;

  float wscWrR[2], wscUR[2];
#pragma unroll
  for (int q = 0; q < 2; q++) {
    int j = ((wave * 2 + q) << 4) + ln;
    wscWrR[q] = wscWr[j];
    wscUR[q]  = wscU[j];
  }

  // ---- init h: fp32 master in regs, i8 copy in LDS ----
  float hreg[2][4];
  float hdq = 2.0f / 127.0f;
  {
    float hqi = 127.0f / 2.0f;
#pragma unroll
    for (int q = 0; q < 2; q++) {
      int j = ((wave * 2 + q) << 4) + ln;
#pragma unroll
      for (int r = 0; r < 4; r++) {
        int m = (lg << 2) + r;
        float v = gru_init[(b0 + m) * D + j];
        hreg[q][r] = v;
        int qv = __float2int_rn(v * hqi);
        qv = qv > 127 ? 127 : (qv < -127 ? -127 : qv);
        hqc[a8off(m, j)] = (signed char)qv;
      }
    }
  }
  __syncthreads();

  const i32x4 z4 = {0, 0, 0, 0};
#pragma unroll 1
  for (int t = 0; t < TS; t++) {
    const unsigned short* f2t = F2T + (size_t)t * (512 * 128);
    float sreg[2][4], greg[2][4];
#pragma unroll
    for (int q = 0; q < 2; q++) {
      int j = ((wave * 2 + q) << 4) + ln;
      ushort8 v = *(const ushort8*)(f2t + (size_t)j * 128 + ((b0 + (lg << 2)) << 1));
#pragma unroll
      for (int r = 0; r < 4; r++) {
        sreg[q][r] = bf2f(v[2 * r]);
        greg[q][r] = bf2f(v[2 * r + 1]);
      }
    }
    // ---- matvec1: c1 = h @ Wr (i8, K=32, frag-pairs) ----
    i32x4 c1[2] = {z4, z4};
#pragma unroll
    for (int p = 0; p < 8; p++) {
      ll2 a2 = *(const ll2*)(hqc + (p << 10) + (lane << 4));
      ll2 w0 = *(const ll2*)(wrq0 + (p << 10));
      ll2 w1 = *(const ll2*)(wrq1 + (p << 10));
      c1[0] = __builtin_amdgcn_mfma_i32_16x16x32_i8(a2[0], w0[0], c1[0], 0, 0, 0);
      c1[0] = __builtin_amdgcn_mfma_i32_16x16x32_i8(a2[1], w0[1], c1[0], 0, 0, 0);
      c1[1] = __builtin_amdgcn_mfma_i32_16x16x32_i8(a2[0], w1[0], c1[1], 0, 0, 0);
      c1[1] = __builtin_amdgcn_mfma_i32_16x16x32_i8(a2[1], w1[1], c1[1], 0, 0, 0);
    }
    // ---- epilogue 1: sr = s * sigmoid(dequant(c1) + g), quantize to i8 (+-8 range) ----
#pragma unroll
    for (int q = 0; q < 2; q++) {
      int j = ((wave * 2 + q) << 4) + ln;
      float d1 = hdq * wscWrR[q];
#pragma unroll
      for (int r = 0; r < 4; r++) {
        int m = (lg << 2) + r;
        float c1f = (float)c1[q][r] * d1;
        float rr = fast_sigmoid(c1f + greg[q][r]);
        float sr = sreg[q][r] * rr;
        int qv = __float2int_rn(sr * (127.0f / 8.0f));
        qv = qv > 127 ? 127 : (qv < -127 ? -127 : qv);
        srqc[a8off(m, j)] = (signed char)qv;
      }
    }
    __syncthreads();
    // ---- matvec2: c2 = sr @ U ----
    i32x4 c2[2] = {z4, z4};
#pragma unroll
    for (int p = 0; p < 8; p++) {
      ll2 a2 = *(const ll2*)(srqc + (p << 10) + (lane << 4));
      ll2 w0 = *(const ll2*)(uq0 + (p << 10));
      ll2 w1 = *(const ll2*)(uq1 + (p << 10));
      c2[0] = __builtin_amdgcn_mfma_i32_16x16x32_i8(a2[0], w0[0], c2[0], 0, 0, 0);
      c2[0] = __builtin_amdgcn_mfma_i32_16x16x32_i8(a2[1], w0[1], c2[0], 0, 0, 0);
      c2[1] = __builtin_amdgcn_mfma_i32_16x16x32_i8(a2[0], w1[0], c2[1], 0, 0, 0);
      c2[1] = __builtin_amdgcn_mfma_i32_16x16x32_i8(a2[1], w1[1], c2[1], 0, 0, 0);
    }
    // ---- epilogue 2: h += 1 + tanh(dequant(c2) + s); write hout + quantized h ----
    {
      float hbn = 2.0f * (float)(t + 1) + 2.0f;
      float hqin = 127.0f / hbn;
#pragma unroll
      for (int q = 0; q < 2; q++) {
        int j = ((wave * 2 + q) << 4) + ln;
        float d2 = (8.0f / 127.0f) * wscUR[q];
#pragma unroll
        for (int r = 0; r < 4; r++) {
          int m = (lg << 2) + r;
          float c2f = (float)c2[q][r] * d2;
          float hn = hreg[q][r] + 1.f + fast_tanh(c2f + sreg[q][r]);
          hreg[q][r] = hn;
          hout[((size_t)t * MB + (b0 + m)) * D + j] = hn;
          int qv = __float2int_rn(hn * hqin);
          qv = qv > 127 ? 127 : (qv < -127 ? -127 : qv);
          hqc[a8off(m, j)] = (signed char)qv;
        }
      }
      hdq = hbn * (1.0f / 127.0f);
    }
    __syncthreads();
  }
}

extern "C" void kernel_launch(void* const* d_in, const int* in_sizes, int n_in,
                              void* d_out, int out_size, void* d_ws, size_t ws_size,
                              hipStream_t stream) {
  const float* c_inp    = (const float*)d_in[0];
  const float* inp      = (const float*)d_in[1];
  const float* gru_init = (const float*)d_in[2];
  const float* att_init = (const float*)d_in[3];
  const float* Wa   = (const float*)d_in[4];
  const float* ba   = (const float*)d_in[5];
  const float* Wb   = (const float*)d_in[6];
  const float* bb   = (const float*)d_in[7];
  const float* Wk   = (const float*)d_in[8];
  const float* bk   = (const float*)d_in[9];
  const float* Wif  = (const float*)d_in[10];
  const float* bif  = (const float*)d_in[11];
  const float* Wfork= (const float*)d_in[12];
  const float* bfork= (const float*)d_in[13];
  const float* Wur  = (const float*)d_in[14];
  const float* U    = (const float*)d_in[15];

  float* out = (float*)d_out;
  float* hid  = out;
  float* attk = out + ATTK_OFF;
  float* attw = out + ATTW_OFF;

  char* ws = (char*)d_ws;
  signed char* WrPK8 = (signed char*)(ws + WS_WRPK8);
  signed char* UPK8  = (signed char*)(ws + WS_UPK8);
  float* wscWr = (float*)(ws + WS_WSC);
  float* wscU  = (float*)(ws + WS_WSC + 2048);
  float* biasR1 = (float*)(ws + WS_BIAS1);
  float* biasR2 = (float*)(ws + WS_BIAS2);
  float* alpha = (float*)(ws + WS_ALPHA);
  float* beta  = (float*)(ws + WS_BETA);
  float* kinc  = (float*)(ws + WS_KINC);
  unsigned short* XB     = (unsigned short*)(ws + WS_X);
  unsigned short* WIFPK  = (unsigned short*)(ws + WS_WIFPK);
  unsigned short* WFORKPK= (unsigned short*)(ws + WS_WFORKPK);
  unsigned short* F2T    = (unsigned short*)(ws + WS_F2T);
  unsigned short* F2B    = (unsigned short*)(ws + WS_F2);

  hipLaunchKernelGGL(col_scales, dim3(2), dim3(256), 0, stream, Wur, U, wscWr, wscU);
  hipLaunchKernelGGL(pack_weights_i8, dim3(1024), dim3(256), 0, stream,
                     Wur, U, wscWr, wscU, WrPK8, UPK8);
  hipLaunchKernelGGL(pack_gemm_w, dim3(512 * 512 / 256), dim3(256), 0, stream,
                     Wif, bif, WIFPK, biasR1, 512, 512, 0);
  hipLaunchKernelGGL(pack_gemm_w, dim3(1024 * 512 / 256), dim3(256), 0, stream,
                     Wfork, bfork, WFORKPK, biasR2, 1536, 1024, 1);
  hipLaunchKernelGGL(abk_kernel, dim3(TS * MB / ABK_ROWS), dim3(64), 0, stream,
                     inp, Wa, ba, Wb, bb, Wk, bk, alpha, beta, kinc);
  hipLaunchKernelGGL(cumsum_kernel, dim3((MB * KMIX + 255) / 256), dim3(256), 0, stream,
                     att_init, kinc, attk);
  hipLaunchKernelGGL(phi_w_kernel, dim3(MB * (TS / WT)), dim3(512), 0, stream,
                     c_inp, alpha, beta, attk, attw);
  hipLaunchKernelGGL((gemm_mfma<1, 1>), dim3(TS * MB / 64, 512 / 128), dim3(512), 0, stream,
                     inp, WIFPK, biasR1, attw, XB, 512);
  hipLaunchKernelGGL((gemm_mfma<0, 1>), dim3(TS * MB / 64, 1024 / 128), dim3(512), 0, stream,
                     XB, WFORKPK, biasR2, (const float*)nullptr, F2B, 1024);
  hipLaunchKernelGGL(pack_f2t, dim3(256 * 8), dim3(256), 0, stream, F2B, F2T);
  hipLaunchKernelGGL(recurrence_i8, dim3(4), dim3(1024), 0, stream,
                     F2T, WrPK8, UPK8, wscWr, wscU, gru_init, hid);
}

// Round 15
// 2085.730 us; speedup vs baseline: 1.4888x; 1.4888x over previous
//
#include <hip/hip_runtime.h>
#include <hip/hip_bf16.h>
#include <math.h>

#define TS   256
#define CTS  512
#define MB   64
#define D    512
#define KMIX 20

// d_out layout (floats): hiddens [TS][MB][D], att_k [TS][MB][KMIX], att_w [TS][MB][D]
#define HID_SIZE  (TS*MB*D)
#define ATTK_OFF  (HID_SIZE)
#define ATTW_OFF  (HID_SIZE + TS*MB*KMIX)

// ws layout (bytes):
#define WS_WRPK8 0            // 256KB  i8 packed reset-Wur
#define WS_UPK8  262144       // 256KB  i8 packed U
#define WS_WSC   524288       // 4KB    wscWr[512], wscU[512]
#define WS_BIAS1 528384       // 2KB    biasR1[512]
#define WS_BIAS2 530432       // 4KB    biasR2[1024]
#define WS_ALPHA 1048576
#define WS_BETA  2359296
#define WS_KINC  3670016
#define WS_X     5242880      // XB bf16 [16384][512] = 16MB
#define WS_F2T   (5242880 + 16777216)   // F2T bf16 16MB; ALSO hosts WIFPK/WFORKPK early (dead before pack_f2t)
#define WS_WIFPK   WS_F2T               // 512KB, dead before F2T written
#define WS_WFORKPK (WS_F2T + 524288)    // 1MB, dead after gemm2
#define WS_F2    38797312     // F2B bf16 [16384][1024] = 32MB

typedef __attribute__((ext_vector_type(2))) long long ll2;
typedef __attribute__((ext_vector_type(4))) int i32x4;
typedef __attribute__((ext_vector_type(8))) short bf16x8;
typedef __attribute__((ext_vector_type(4))) float f32x4;
typedef __attribute__((ext_vector_type(8))) unsigned short ushort8;

__device__ __forceinline__ unsigned short f2bf(float v) {
  __hip_bfloat16 h = __float2bfloat16(v);
  union { __hip_bfloat16 h; unsigned short u; } cvt; cvt.h = h;
  return cvt.u;
}
__device__ __forceinline__ float bf2f(unsigned short u) {
  return __uint_as_float(((unsigned)u) << 16);
}

// ---------------- K0a: per-output-column weight scales (recurrence i8) ----------------
__global__ __launch_bounds__(256) void col_scales(const float* __restrict__ Wur,
                                                  const float* __restrict__ U,
                                                  float* __restrict__ wscWr,
                                                  float* __restrict__ wscU) {
  int j = blockIdx.x * 256 + threadIdx.x;
  if (j >= 512) return;
  float mw = 0.f, mu = 0.f;
  for (int k = 0; k < 512; k++) {
    mw = fmaxf(mw, fabsf(Wur[k * 1024 + 512 + j]));
    mu = fmaxf(mu, fabsf(U[k * 512 + j]));
  }
  wscWr[j] = fmaxf(mw, 1e-20f) * (1.0f / 127.0f);
  wscU[j]  = fmaxf(mu, 1e-20f) * (1.0f / 127.0f);
}

// ---------------- K0b: pack recurrence weights to i8, pair-interleaved B-frag layout ----
__global__ __launch_bounds__(256) void pack_weights_i8(const float* __restrict__ Wur,
                                                       const float* __restrict__ U,
                                                       const float* __restrict__ wscWr,
                                                       const float* __restrict__ wscU,
                                                       signed char* __restrict__ WrPK8,
                                                       signed char* __restrict__ UPK8) {
  int o = blockIdx.x * 256 + threadIdx.x;   // 0..262143
  int e = o & 7, half = (o >> 3) & 1, l = (o >> 4) & 63, p = (o >> 10) & 7, nt = o >> 13;
  int k = (2 * p + half) * 32 + ((l >> 4) & 3) * 8 + e;
  int n = nt * 16 + (l & 15);
  float i1 = __builtin_amdgcn_rcpf(wscWr[n]);
  float i2 = __builtin_amdgcn_rcpf(wscU[n]);
  int q1 = __float2int_rn(Wur[k * 1024 + 512 + n] * i1);
  int q2 = __float2int_rn(U[k * 512 + n] * i2);
  q1 = q1 > 127 ? 127 : (q1 < -127 ? -127 : q1);
  q2 = q2 > 127 ? 127 : (q2 < -127 ? -127 : q2);
  WrPK8[o] = (signed char)q1;
  UPK8[o]  = (signed char)q2;
}

// ---------------- K0c: pack GEMM weights to bf16 B-frag layout (+remapped bias) ----------
__global__ __launch_bounds__(256) void pack_gemm_w(const float* __restrict__ W,
                                                   const float* __restrict__ bias,
                                                   unsigned short* __restrict__ out,
                                                   float* __restrict__ biasR,
                                                   int ldw, int N, int remap) {
  int idx = blockIdx.x * 256 + threadIdx.x;   // N*512 total
  int e = idx & 7, l = (idx >> 3) & 63, f = idx >> 9;
  int kt = f & 15, nt = f >> 4;
  int k = kt * 32 + ((l >> 4) << 3) + e;
  int n = (nt << 4) + (l & 15);
  int col = (remap && n >= 512) ? n + 512 : n;
  out[idx] = f2bf(W[(size_t)k * ldw + col]);
  if (idx < N) biasR[idx] = bias[(remap && idx >= 512) ? idx + 512 : idx];
}

// ---------------- K1: alpha = inp@Wa+ba (log domain), beta, kinc ----------------
#define ABK_ROWS 8
__global__ __launch_bounds__(64) void abk_kernel(const float* __restrict__ inp,
                                                 const float* __restrict__ Wa, const float* __restrict__ ba,
                                                 const float* __restrict__ Wb, const float* __restrict__ bb_,
                                                 const float* __restrict__ Wk, const float* __restrict__ bk,
                                                 float* __restrict__ alpha, float* __restrict__ beta,
                                                 float* __restrict__ kinc) {
  __shared__ float rows[ABK_ROWS][D];
  int tb0 = blockIdx.x * ABK_ROWS;
  for (int x = threadIdx.x; x < ABK_ROWS * D; x += 64)
    rows[x >> 9][x & 511] = inp[(size_t)tb0 * D + x];
  __syncthreads();
  int j = threadIdx.x;
  if (j >= 3 * KMIX) return;
  int wj = j % KMIX;
  int which = j / KMIX;
  const float* W = (which == 0) ? Wa : ((which == 1) ? Wb : Wk);
  const float* B = (which == 0) ? ba : ((which == 1) ? bb_ : bk);
  float acc[ABK_ROWS];
  float bias = B[wj];
#pragma unroll
  for (int r = 0; r < ABK_ROWS; r++) acc[r] = bias;
  for (int i = 0; i < D; i++) {
    float wv = W[i * KMIX + wj];
#pragma unroll
    for (int r = 0; r < ABK_ROWS; r++) acc[r] += rows[r][i] * wv;
  }
  for (int r = 0; r < ABK_ROWS; r++) {
    int tb = tb0 + r;
    float v = acc[r];
    if (which == 0) alpha[tb * KMIX + wj] = v;
    else if (which == 1) beta[tb * KMIX + wj] = expf(v);
    else kinc[tb * KMIX + wj] = expf(v);
  }
}

// ---------------- K2: k cumsum over t; writes att_k region of d_out ----------------
__global__ __launch_bounds__(256) void cumsum_kernel(const float* __restrict__ att_init,
                                                     const float* __restrict__ kinc,
                                                     float* __restrict__ kout) {
  int idx = blockIdx.x * 256 + threadIdx.x;
  if (idx >= MB * KMIX) return;
  float k = att_init[idx];
  for (int t = 0; t < TS; t++) {
    k += kinc[t * MB * KMIX + idx];
    kout[t * MB * KMIX + idx] = k;
  }
}

// ---------------- K3: phi + w GEMM; writes att_w region of d_out ----------------
// WT=16 (round-13 measured-best; WT=32 regressed ~90us via occupancy loss).
#define WT 16
__global__ __launch_bounds__(512) void phi_w_kernel(const float* __restrict__ c_inp,
                                                    const float* __restrict__ alpha,
                                                    const float* __restrict__ beta,
                                                    const float* __restrict__ katt,
                                                    float* __restrict__ wout) {
  int b  = blockIdx.x / (TS / WT);
  int t0 = (blockIdx.x % (TS / WT)) * WT;
  __shared__ float phi[WT][CTS];
  __shared__ float pa[WT][KMIX], pb[WT][KMIX], pk[WT][KMIX];
  for (int x = threadIdx.x; x < WT * KMIX; x += 512) {
    int tt = x / KMIX, j = x % KMIX;
    int tb = (t0 + tt) * MB + b;
    pa[tt][j] = alpha[tb * KMIX + j];
    pb[tt][j] = beta[tb * KMIX + j];
    pk[tt][j] = katt[tb * KMIX + j];
  }
  __syncthreads();
  {
    int c = threadIdx.x;
    float fc = (float)c;
#pragma unroll
    for (int tt = 0; tt < WT; tt++) {
      float s = 0.f;
#pragma unroll
      for (int j = 0; j < KMIX; j++) {
        float dd = pk[tt][j] - fc;
        s += expf(pa[tt][j] - pb[tt][j] * dd * dd);
      }
      phi[tt][c] = s;
    }
  }
  __syncthreads();
  {
    int d = threadIdx.x;
    float acc[WT];
#pragma unroll
    for (int tt = 0; tt < WT; tt++) acc[tt] = 0.f;
    const float* cb = c_inp + (size_t)b * D + d;
    for (int c2 = 0; c2 < CTS; c2++) {
      float cv = cb[(size_t)c2 * (MB * D)];
#pragma unroll
      for (int tt = 0; tt < WT; tt++) acc[tt] += phi[tt][c2] * cv;
    }
    for (int tt = 0; tt < WT; tt++)
      wout[((size_t)(t0 + tt) * MB + b) * D + d] = acc[tt];
  }
}

// ---------------- K4/K5: bf16 MFMA GEMM, 64x128 tile, 8 waves ----------------
template<int AF32, int OUTBF>
__global__ __launch_bounds__(512) void gemm_mfma(const void* __restrict__ Av,
                                                 const unsigned short* __restrict__ BPK,
                                                 const float* __restrict__ biasR,
                                                 const float* __restrict__ wadd,
                                                 void* __restrict__ Cv, int Nout) {
  __shared__ unsigned short abf[4][16 * 512];   // 64KB
  const int tid = threadIdx.x, wave = tid >> 6, lane = tid & 63;
  const int lg = lane >> 4, ln = lane & 15;
  const int wm = wave & 3, wn = wave >> 2;
  const int m0 = blockIdx.x * 64, n0 = blockIdx.y * 128;
  const int Lsrd = lane ^ ((lane >> 3) & 7);

#pragma unroll
  for (int i = 0; i < 8; i++) {
    int g = (i * 512 + tid) * 8;
    int row = g >> 9, col = g & 511;
    ushort8 u;
    if (AF32) {
      const float* A = (const float*)Av;
      float4 v0 = *(const float4*)(A + (size_t)(m0 + row) * 512 + col);
      float4 v1 = *(const float4*)(A + (size_t)(m0 + row) * 512 + col + 4);
      u[0] = f2bf(v0.x); u[1] = f2bf(v0.y); u[2] = f2bf(v0.z); u[3] = f2bf(v0.w);
      u[4] = f2bf(v1.x); u[5] = f2bf(v1.y); u[6] = f2bf(v1.z); u[7] = f2bf(v1.w);
    } else {
      const unsigned short* A = (const unsigned short*)Av;
      u = *(const ushort8*)(A + (size_t)(m0 + row) * 512 + col);
    }
    int strip = row >> 4, m = row & 15;
    int L = (((col >> 3) & 3) << 4) | m;
    int Ls = L ^ ((L >> 3) & 7);
    *(ushort8*)(&abf[strip][((col >> 5) << 9) + (Ls << 3)]) = u;
  }
  __syncthreads();

  const f32x4 zero4 = {0.f, 0.f, 0.f, 0.f};
  f32x4 acc[4] = {zero4, zero4, zero4, zero4};
  const bf16x8* BP = (const bf16x8*)BPK;
  const int ntbase = (n0 >> 4) + wn * 4;
#pragma unroll
  for (int kt = 0; kt < 16; kt++) {
    bf16x8 a = *(const bf16x8*)(&abf[wm][(kt << 9) + (Lsrd << 3)]);
#pragma unroll
    for (int q = 0; q < 4; q++)
      acc[q] = __builtin_amdgcn_mfma_f32_16x16x32_bf16(
          a, BP[(((ntbase + q) * 16 + kt) << 6) + lane], acc[q], 0, 0, 0);
  }

#pragma unroll
  for (int q = 0; q < 4; q++) {
    int col = n0 + ((wn * 4 + q) << 4) + ln;
    float bb = biasR[col];
#pragma unroll
    for (int r = 0; r < 4; r++) {
      int row = m0 + (wm << 4) + (lg << 2) + r;
      float v = acc[q][r] + bb;
      if (wadd) v += wadd[(size_t)row * 512 + col];
      if (OUTBF) ((unsigned short*)Cv)[(size_t)row * Nout + col] = f2bf(v);
      else       ((float*)Cv)[(size_t)row * Nout + col] = v;
    }
  }
}

// ---------------- K5b: transpose+pack F2B (bf16) -> F2T bf16 [t][j<512][m][2(s,g)] ------
__global__ __launch_bounds__(256) void pack_f2t(const unsigned short* __restrict__ F2B,
                                                unsigned short* __restrict__ F2T) {
  __shared__ unsigned short ts_[64][66], tg_[64][66];
  int t = blockIdx.x >> 3, jb = (blockIdx.x & 7) << 6;
  const unsigned short* src = F2B + (size_t)t * 64 * 1024;
  for (int mm = 0; mm < 64; mm += 4) {
    int m = mm + (threadIdx.x >> 6);
    int c = threadIdx.x & 63;
    ts_[m][c] = src[(size_t)m * 1024 + jb + c];
    tg_[m][c] = src[(size_t)m * 1024 + 512 + jb + c];
  }
  __syncthreads();
  unsigned short* dst = F2T + ((size_t)t * 512 + jb) * 128;
  for (int base = threadIdx.x; base < 64 * 128; base += 256) {
    int j = base >> 7, idx = base & 127, m = idx >> 1, sel = idx & 1;
    dst[(size_t)j * 128 + idx] = sel ? tg_[m][j] : ts_[m][j];
  }
}

// ---------------- K6: i8 MFMA recurrence, 1024 thr, 128KB of weights LDS-resident ----------
// Pages 0-1 of Wr and U (25% of the 512KB/step stream) pinned in LDS once; B-frag reads
// become ds_read_b128 at lane*16 (2-way aliasing = free). Pages 2-7 streamed from L2 as
// before (plain inline loads, compiler-scheduled). Everything else round-11 verbatim.
__device__ __forceinline__ int a8off(int m, int j) {
  return ((j >> 6) << 10) + (((((j >> 3) & 3) << 4) + m) << 4) + (((j >> 5) & 1) << 3) + (j & 7);
}
__device__ __forceinline__ float fast_sigmoid(float x) {
  return __builtin_amdgcn_rcpf(1.f + __expf(-x));
}
__device__ __forceinline__ float fast_tanh(float x) {
  x = fminf(15.f, fmaxf(-15.f, x));
  float e = __expf(2.f * x);
  return 1.f - 2.f * __builtin_amdgcn_rcpf(e + 1.f);
}

__global__ __launch_bounds__(1024) void recurrence_i8(
    const unsigned short* __restrict__ F2T,
    const signed char* __restrict__ WrPK8,
    const signed char* __restrict__ UPK8,
    const float* __restrict__ wscWr,
    const float* __restrict__ wscU,
    const float* __restrict__ gru_init,
    float* __restrict__ hout) {
  __shared__ long long hq8[1024];     // 8KB i8 A-buffer (h)
  __shared__ long long srq8[1024];    // 8KB i8 A-buffer (sr)
  __shared__ long long wldsWr[8192];  // 64KB: Wr pages 0-1, chunk idx (nt*2+p)*64 + l
  __shared__ long long wldsU[8192];   // 64KB: U  pages 0-1
  signed char* hqc  = (signed char*)hq8;
  signed char* srqc = (signed char*)srq8;
  const int tid  = threadIdx.x;
  const int wave = tid >> 6;        // 0..15
  const int lane = tid & 63;
  const int lg = lane >> 4;
  const int ln = lane & 15;
  const int b0 = blockIdx.x * 16;

  const signed char* wrq0 = WrPK8 + (size_t)(wave * 2 + 0) * 8192 + lane * 16;
  const signed char* wrq1 = WrPK8 + (size_t)(wave * 2 + 1) * 8192 + lane * 16;
  const signed char* uq0  = UPK8  + (size_t)(wave * 2 + 0) * 8192 + lane * 16;
  const signed char* uq1  = UPK8  + (size_t)(wave * 2 + 1) * 8192 + lane * 16;

  // LDS-resident page pointers (16B-chunk index = (nt*2+p)*64 + lane)
  const ll2* wl0 = (const ll2*)wldsWr + ((wave * 2 + 0) * 2) * 64 + lane;
  const ll2* wl1 = (const ll2*)wldsWr + ((wave * 2 + 1) * 2) * 64 + lane;
  const ll2* ul0 = (const ll2*)wldsU  + ((wave * 2 + 0) * 2) * 64 + lane;
  const ll2* ul1 = (const ll2*)wldsU  + ((wave * 2 + 1) * 2) * 64 + lane;

  // ---- stage pages 0-1 of both matrices to LDS (once) ----
  {
    const ll2* s1 = (const ll2*)WrPK8;
    const ll2* s2 = (const ll2*)UPK8;
    ll2* d1 = (ll2*)wldsWr;
    ll2* d2 = (ll2*)wldsU;
#pragma unroll
    for (int c = 0; c < 4; c++) {
      int i = tid + c * 1024;                 // LDS 16B-chunk 0..4095
      int l = i & 63, p = (i >> 6) & 1, nt = i >> 7;
      int g = (nt * 8 + p) * 64 + l;          // global 16B-chunk
      d1[i] = s1[g];
      d2[i] = s2[g];
    }
  }

  float wscWrR[2], wscUR[2];
#pragma unroll
  for (int q = 0; q < 2; q++) {
    int j = ((wave * 2 + q) << 4) + ln;
    wscWrR[q] = wscWr[j];
    wscUR[q]  = wscU[j];
  }

  // ---- init h: fp32 master in regs, i8 copy in LDS ----
  float hreg[2][4];
  float hdq = 2.0f / 127.0f;
  {
    float hqi = 127.0f / 2.0f;
#pragma unroll
    for (int q = 0; q < 2; q++) {
      int j = ((wave * 2 + q) << 4) + ln;
#pragma unroll
      for (int r = 0; r < 4; r++) {
        int m = (lg << 2) + r;
        float v = gru_init[(b0 + m) * D + j];
        hreg[q][r] = v;
        int qv = __float2int_rn(v * hqi);
        qv = qv > 127 ? 127 : (qv < -127 ? -127 : qv);
        hqc[a8off(m, j)] = (signed char)qv;
      }
    }
  }
  __syncthreads();

  const i32x4 z4 = {0, 0, 0, 0};
#pragma unroll 1
  for (int t = 0; t < TS; t++) {
    const unsigned short* f2t = F2T + (size_t)t * (512 * 128);
    float sreg[2][4], greg[2][4];
#pragma unroll
    for (int q = 0; q < 2; q++) {
      int j = ((wave * 2 + q) << 4) + ln;
      ushort8 v = *(const ushort8*)(f2t + (size_t)j * 128 + ((b0 + (lg << 2)) << 1));
#pragma unroll
      for (int r = 0; r < 4; r++) {
        sreg[q][r] = bf2f(v[2 * r]);
        greg[q][r] = bf2f(v[2 * r + 1]);
      }
    }
    // ---- matvec1: pages 0-1 from LDS, 2-7 from L2 ----
    i32x4 c1[2] = {z4, z4};
#pragma unroll
    for (int p = 0; p < 2; p++) {
      ll2 a2 = *(const ll2*)(hqc + (p << 10) + (lane << 4));
      ll2 w0 = wl0[p << 6];
      ll2 w1 = wl1[p << 6];
      c1[0] = __builtin_amdgcn_mfma_i32_16x16x32_i8(a2[0], w0[0], c1[0], 0, 0, 0);
      c1[0] = __builtin_amdgcn_mfma_i32_16x16x32_i8(a2[1], w0[1], c1[0], 0, 0, 0);
      c1[1] = __builtin_amdgcn_mfma_i32_16x16x32_i8(a2[0], w1[0], c1[1], 0, 0, 0);
      c1[1] = __builtin_amdgcn_mfma_i32_16x16x32_i8(a2[1], w1[1], c1[1], 0, 0, 0);
    }
#pragma unroll
    for (int p = 2; p < 8; p++) {
      ll2 a2 = *(const ll2*)(hqc + (p << 10) + (lane << 4));
      ll2 w0 = *(const ll2*)(wrq0 + (p << 10));
      ll2 w1 = *(const ll2*)(wrq1 + (p << 10));
      c1[0] = __builtin_amdgcn_mfma_i32_16x16x32_i8(a2[0], w0[0], c1[0], 0, 0, 0);
      c1[0] = __builtin_amdgcn_mfma_i32_16x16x32_i8(a2[1], w0[1], c1[0], 0, 0, 0);
      c1[1] = __builtin_amdgcn_mfma_i32_16x16x32_i8(a2[0], w1[0], c1[1], 0, 0, 0);
      c1[1] = __builtin_amdgcn_mfma_i32_16x16x32_i8(a2[1], w1[1], c1[1], 0, 0, 0);
    }
    // ---- epilogue 1: sr = s * sigmoid(dequant(c1) + g), quantize to i8 (+-8 range) ----
#pragma unroll
    for (int q = 0; q < 2; q++) {
      int j = ((wave * 2 + q) << 4) + ln;
      float d1 = hdq * wscWrR[q];
#pragma unroll
      for (int r = 0; r < 4; r++) {
        int m = (lg << 2) + r;
        float c1f = (float)c1[q][r] * d1;
        float rr = fast_sigmoid(c1f + greg[q][r]);
        float sr = sreg[q][r] * rr;
        int qv = __float2int_rn(sr * (127.0f / 8.0f));
        qv = qv > 127 ? 127 : (qv < -127 ? -127 : qv);
        srqc[a8off(m, j)] = (signed char)qv;
      }
    }
    __syncthreads();
    // ---- matvec2: pages 0-1 from LDS, 2-7 from L2 ----
    i32x4 c2[2] = {z4, z4};
#pragma unroll
    for (int p = 0; p < 2; p++) {
      ll2 a2 = *(const ll2*)(srqc + (p << 10) + (lane << 4));
      ll2 w0 = ul0[p << 6];
      ll2 w1 = ul1[p << 6];
      c2[0] = __builtin_amdgcn_mfma_i32_16x16x32_i8(a2[0], w0[0], c2[0], 0, 0, 0);
      c2[0] = __builtin_amdgcn_mfma_i32_16x16x32_i8(a2[1], w0[1], c2[0], 0, 0, 0);
      c2[1] = __builtin_amdgcn_mfma_i32_16x16x32_i8(a2[0], w1[0], c2[1], 0, 0, 0);
      c2[1] = __builtin_amdgcn_mfma_i32_16x16x32_i8(a2[1], w1[1], c2[1], 0, 0, 0);
    }
#pragma unroll
    for (int p = 2; p < 8; p++) {
      ll2 a2 = *(const ll2*)(srqc + (p << 10) + (lane << 4));
      ll2 w0 = *(const ll2*)(uq0 + (p << 10));
      ll2 w1 = *(const ll2*)(uq1 + (p << 10));
      c2[0] = __builtin_amdgcn_mfma_i32_16x16x32_i8(a2[0], w0[0], c2[0], 0, 0, 0);
      c2[0] = __builtin_amdgcn_mfma_i32_16x16x32_i8(a2[1], w0[1], c2[0], 0, 0, 0);
      c2[1] = __builtin_amdgcn_mfma_i32_16x16x32_i8(a2[0], w1[0], c2[1], 0, 0, 0);
      c2[1] = __builtin_amdgcn_mfma_i32_16x16x32_i8(a2[1], w1[1], c2[1], 0, 0, 0);
    }
    // ---- epilogue 2: h += 1 + tanh(dequant(c2) + s); write hout + quantized h ----
    {
      float hbn = 2.0f * (float)(t + 1) + 2.0f;
      float hqin = 127.0f / hbn;
#pragma unroll
      for (int q = 0; q < 2; q++) {
        int j = ((wave * 2 + q) << 4) + ln;
        float d2 = (8.0f / 127.0f) * wscUR[q];
#pragma unroll
        for (int r = 0; r < 4; r++) {
          int m = (lg << 2) + r;
          float c2f = (float)c2[q][r] * d2;
          float hn = hreg[q][r] + 1.f + fast_tanh(c2f + sreg[q][r]);
          hreg[q][r] = hn;
          hout[((size_t)t * MB + (b0 + m)) * D + j] = hn;
          int qv = __float2int_rn(hn * hqin);
          qv = qv > 127 ? 127 : (qv < -127 ? -127 : qv);
          hqc[a8off(m, j)] = (signed char)qv;
        }
      }
      hdq = hbn * (1.0f / 127.0f);
    }
    __syncthreads();
  }
}

extern "C" void kernel_launch(void* const* d_in, const int* in_sizes, int n_in,
                              void* d_out, int out_size, void* d_ws, size_t ws_size,
                              hipStream_t stream) {
  const float* c_inp    = (const float*)d_in[0];
  const float* inp      = (const float*)d_in[1];
  const float* gru_init = (const float*)d_in[2];
  const float* att_init = (const float*)d_in[3];
  const float* Wa   = (const float*)d_in[4];
  const float* ba   = (const float*)d_in[5];
  const float* Wb   = (const float*)d_in[6];
  const float* bb   = (const float*)d_in[7];
  const float* Wk   = (const float*)d_in[8];
  const float* bk   = (const float*)d_in[9];
  const float* Wif  = (const float*)d_in[10];
  const float* bif  = (const float*)d_in[11];
  const float* Wfork= (const float*)d_in[12];
  const float* bfork= (const float*)d_in[13];
  const float* Wur  = (const float*)d_in[14];
  const float* U    = (const float*)d_in[15];

  float* out = (float*)d_out;
  float* hid  = out;
  float* attk = out + ATTK_OFF;
  float* attw = out + ATTW_OFF;

  char* ws = (char*)d_ws;
  signed char* WrPK8 = (signed char*)(ws + WS_WRPK8);
  signed char* UPK8  = (signed char*)(ws + WS_UPK8);
  float* wscWr = (float*)(ws + WS_WSC);
  float* wscU  = (float*)(ws + WS_WSC + 2048);
  float* biasR1 = (float*)(ws + WS_BIAS1);
  float* biasR2 = (float*)(ws + WS_BIAS2);
  float* alpha = (float*)(ws + WS_ALPHA);
  float* beta  = (float*)(ws + WS_BETA);
  float* kinc  = (float*)(ws + WS_KINC);
  unsigned short* XB     = (unsigned short*)(ws + WS_X);
  unsigned short* WIFPK  = (unsigned short*)(ws + WS_WIFPK);
  unsigned short* WFORKPK= (unsigned short*)(ws + WS_WFORKPK);
  unsigned short* F2T    = (unsigned short*)(ws + WS_F2T);
  unsigned short* F2B    = (unsigned short*)(ws + WS_F2);

  hipLaunchKernelGGL(col_scales, dim3(2), dim3(256), 0, stream, Wur, U, wscWr, wscU);
  hipLaunchKernelGGL(pack_weights_i8, dim3(1024), dim3(256), 0, stream,
                     Wur, U, wscWr, wscU, WrPK8, UPK8);
  hipLaunchKernelGGL(pack_gemm_w, dim3(512 * 512 / 256), dim3(256), 0, stream,
                     Wif, bif, WIFPK, biasR1, 512, 512, 0);
  hipLaunchKernelGGL(pack_gemm_w, dim3(1024 * 512 / 256), dim3(256), 0, stream,
                     Wfork, bfork, WFORKPK, biasR2, 1536, 1024, 1);
  hipLaunchKernelGGL(abk_kernel, dim3(TS * MB / ABK_ROWS), dim3(64), 0, stream,
                     inp, Wa, ba, Wb, bb, Wk, bk, alpha, beta, kinc);
  hipLaunchKernelGGL(cumsum_kernel, dim3((MB * KMIX + 255) / 256), dim3(256), 0, stream,
                     att_init, kinc, attk);
  hipLaunchKernelGGL(phi_w_kernel, dim3(MB * (TS / WT)), dim3(512), 0, stream,
                     c_inp, alpha, beta, attk, attw);
  hipLaunchKernelGGL((gemm_mfma<1, 1>), dim3(TS * MB / 64, 512 / 128), dim3(512), 0, stream,
                     inp, WIFPK, biasR1, attw, XB, 512);
  hipLaunchKernelGGL((gemm_mfma<0, 1>), dim3(TS * MB / 64, 1024 / 128), dim3(512), 0, stream,
                     XB, WFORKPK, biasR2, (const float*)nullptr, F2B, 1024);
  hipLaunchKernelGGL(pack_f2t, dim3(256 * 8), dim3(256), 0, stream, F2B, F2T);
  hipLaunchKernelGGL(recurrence_i8, dim3(4), dim3(1024), 0, stream,
                     F2T, WrPK8, UPK8, wscWr, wscU, gru_init, hid);
}

// Round 16
// 2040.862 us; speedup vs baseline: 1.5215x; 1.0220x over previous
//
#include <hip/hip_runtime.h>
#include <hip/hip_bf16.h>
#include <math.h>

#define TS   256
#define CTS  512
#define MB   64
#define D    512
#define KMIX 20

// d_out layout (floats): hiddens [TS][MB][D], att_k [TS][MB][KMIX], att_w [TS][MB][D]
#define HID_SIZE  (TS*MB*D)
#define ATTK_OFF  (HID_SIZE)
#define ATTW_OFF  (HID_SIZE + TS*MB*KMIX)

// ws layout (bytes):
#define WS_WRPK8 0            // 256KB  i8 packed reset-Wur
#define WS_UPK8  262144       // 256KB  i8 packed U
#define WS_WSC   524288       // 4KB    wscWr[512], wscU[512]
#define WS_BIAS1 528384       // 2KB    biasR1[512]
#define WS_BIAS2 530432       // 4KB    biasR2[1024]
#define WS_ALPHA 1048576
#define WS_BETA  2359296
#define WS_KINC  3670016
#define WS_X     5242880      // XB bf16 [16384][512] = 16MB
#define WS_F2T   (5242880 + 16777216)   // F2T bf16 16MB; ALSO hosts WIFPK/WFORKPK early (dead before pack_f2t)
#define WS_WIFPK   WS_F2T               // 512KB, dead before F2T written
#define WS_WFORKPK (WS_F2T + 524288)    // 1MB, dead after gemm2
#define WS_F2    38797312     // F2B bf16 [16384][1024] = 32MB

typedef __attribute__((ext_vector_type(2))) long long ll2;
typedef __attribute__((ext_vector_type(4))) int i32x4;
typedef __attribute__((ext_vector_type(8))) short bf16x8;
typedef __attribute__((ext_vector_type(4))) float f32x4;
typedef __attribute__((ext_vector_type(8))) unsigned short ushort8;

__device__ __forceinline__ unsigned short f2bf(float v) {
  __hip_bfloat16 h = __float2bfloat16(v);
  union { __hip_bfloat16 h; unsigned short u; } cvt; cvt.h = h;
  return cvt.u;
}
__device__ __forceinline__ float bf2f(unsigned short u) {
  return __uint_as_float(((unsigned)u) << 16);
}

// ---------------- K0a: per-output-column weight scales (recurrence i8) ----------------
__global__ __launch_bounds__(256) void col_scales(const float* __restrict__ Wur,
                                                  const float* __restrict__ U,
                                                  float* __restrict__ wscWr,
                                                  float* __restrict__ wscU) {
  int j = blockIdx.x * 256 + threadIdx.x;
  if (j >= 512) return;
  float mw = 0.f, mu = 0.f;
  for (int k = 0; k < 512; k++) {
    mw = fmaxf(mw, fabsf(Wur[k * 1024 + 512 + j]));
    mu = fmaxf(mu, fabsf(U[k * 512 + j]));
  }
  wscWr[j] = fmaxf(mw, 1e-20f) * (1.0f / 127.0f);
  wscU[j]  = fmaxf(mu, 1e-20f) * (1.0f / 127.0f);
}

// ---------------- K0b: pack recurrence weights to i8, pair-interleaved B-frag layout ----
__global__ __launch_bounds__(256) void pack_weights_i8(const float* __restrict__ Wur,
                                                       const float* __restrict__ U,
                                                       const float* __restrict__ wscWr,
                                                       const float* __restrict__ wscU,
                                                       signed char* __restrict__ WrPK8,
                                                       signed char* __restrict__ UPK8) {
  int o = blockIdx.x * 256 + threadIdx.x;   // 0..262143
  int e = o & 7, half = (o >> 3) & 1, l = (o >> 4) & 63, p = (o >> 10) & 7, nt = o >> 13;
  int k = (2 * p + half) * 32 + ((l >> 4) & 3) * 8 + e;
  int n = nt * 16 + (l & 15);
  float i1 = __builtin_amdgcn_rcpf(wscWr[n]);
  float i2 = __builtin_amdgcn_rcpf(wscU[n]);
  int q1 = __float2int_rn(Wur[k * 1024 + 512 + n] * i1);
  int q2 = __float2int_rn(U[k * 512 + n] * i2);
  q1 = q1 > 127 ? 127 : (q1 < -127 ? -127 : q1);
  q2 = q2 > 127 ? 127 : (q2 < -127 ? -127 : q2);
  WrPK8[o] = (signed char)q1;
  UPK8[o]  = (signed char)q2;
}

// ---------------- K0c: pack GEMM weights to bf16 B-frag layout (+remapped bias) ----------
__global__ __launch_bounds__(256) void pack_gemm_w(const float* __restrict__ W,
                                                   const float* __restrict__ bias,
                                                   unsigned short* __restrict__ out,
                                                   float* __restrict__ biasR,
                                                   int ldw, int N, int remap) {
  int idx = blockIdx.x * 256 + threadIdx.x;   // N*512 total
  int e = idx & 7, l = (idx >> 3) & 63, f = idx >> 9;
  int kt = f & 15, nt = f >> 4;
  int k = kt * 32 + ((l >> 4) << 3) + e;
  int n = (nt << 4) + (l & 15);
  int col = (remap && n >= 512) ? n + 512 : n;
  out[idx] = f2bf(W[(size_t)k * ldw + col]);
  if (idx < N) biasR[idx] = bias[(remap && idx >= 512) ? idx + 512 : idx];
}

// ---------------- K1: alpha = inp@Wa+ba (log domain), beta, kinc ----------------
#define ABK_ROWS 8
__global__ __launch_bounds__(64) void abk_kernel(const float* __restrict__ inp,
                                                 const float* __restrict__ Wa, const float* __restrict__ ba,
                                                 const float* __restrict__ Wb, const float* __restrict__ bb_,
                                                 const float* __restrict__ Wk, const float* __restrict__ bk,
                                                 float* __restrict__ alpha, float* __restrict__ beta,
                                                 float* __restrict__ kinc) {
  __shared__ float rows[ABK_ROWS][D];
  int tb0 = blockIdx.x * ABK_ROWS;
  for (int x = threadIdx.x; x < ABK_ROWS * D; x += 64)
    rows[x >> 9][x & 511] = inp[(size_t)tb0 * D + x];
  __syncthreads();
  int j = threadIdx.x;
  if (j >= 3 * KMIX) return;
  int wj = j % KMIX;
  int which = j / KMIX;
  const float* W = (which == 0) ? Wa : ((which == 1) ? Wb : Wk);
  const float* B = (which == 0) ? ba : ((which == 1) ? bb_ : bk);
  float acc[ABK_ROWS];
  float bias = B[wj];
#pragma unroll
  for (int r = 0; r < ABK_ROWS; r++) acc[r] = bias;
  for (int i = 0; i < D; i++) {
    float wv = W[i * KMIX + wj];
#pragma unroll
    for (int r = 0; r < ABK_ROWS; r++) acc[r] += rows[r][i] * wv;
  }
  for (int r = 0; r < ABK_ROWS; r++) {
    int tb = tb0 + r;
    float v = acc[r];
    if (which == 0) alpha[tb * KMIX + wj] = v;
    else if (which == 1) beta[tb * KMIX + wj] = expf(v);
    else kinc[tb * KMIX + wj] = expf(v);
  }
}

// ---------------- K2: k cumsum over t; writes att_k region of d_out ----------------
__global__ __launch_bounds__(256) void cumsum_kernel(const float* __restrict__ att_init,
                                                     const float* __restrict__ kinc,
                                                     float* __restrict__ kout) {
  int idx = blockIdx.x * 256 + threadIdx.x;
  if (idx >= MB * KMIX) return;
  float k = att_init[idx];
  for (int t = 0; t < TS; t++) {
    k += kinc[t * MB * KMIX + idx];
    kout[t * MB * KMIX + idx] = k;
  }
}

// ---------------- K3: phi + w GEMM; writes att_w region of d_out ----------------
#define WT 16
__global__ __launch_bounds__(512) void phi_w_kernel(const float* __restrict__ c_inp,
                                                    const float* __restrict__ alpha,
                                                    const float* __restrict__ beta,
                                                    const float* __restrict__ katt,
                                                    float* __restrict__ wout) {
  int b  = blockIdx.x / (TS / WT);
  int t0 = (blockIdx.x % (TS / WT)) * WT;
  __shared__ float phi[WT][CTS];
  __shared__ float pa[WT][KMIX], pb[WT][KMIX], pk[WT][KMIX];
  for (int x = threadIdx.x; x < WT * KMIX; x += 512) {
    int tt = x / KMIX, j = x % KMIX;
    int tb = (t0 + tt) * MB + b;
    pa[tt][j] = alpha[tb * KMIX + j];
    pb[tt][j] = beta[tb * KMIX + j];
    pk[tt][j] = katt[tb * KMIX + j];
  }
  __syncthreads();
  {
    int c = threadIdx.x;
    float fc = (float)c;
#pragma unroll
    for (int tt = 0; tt < WT; tt++) {
      float s = 0.f;
#pragma unroll
      for (int j = 0; j < KMIX; j++) {
        float dd = pk[tt][j] - fc;
        s += expf(pa[tt][j] - pb[tt][j] * dd * dd);
      }
      phi[tt][c] = s;
    }
  }
  __syncthreads();
  {
    int d = threadIdx.x;
    float acc[WT];
#pragma unroll
    for (int tt = 0; tt < WT; tt++) acc[tt] = 0.f;
    const float* cb = c_inp + (size_t)b * D + d;
    for (int c2 = 0; c2 < CTS; c2++) {
      float cv = cb[(size_t)c2 * (MB * D)];
#pragma unroll
      for (int tt = 0; tt < WT; tt++) acc[tt] += phi[tt][c2] * cv;
    }
    for (int tt = 0; tt < WT; tt++)
      wout[((size_t)(t0 + tt) * MB + b) * D + d] = acc[tt];
  }
}

// ---------------- K4/K5: bf16 MFMA GEMM, 64x128 tile, 8 waves ----------------
template<int AF32, int OUTBF>
__global__ __launch_bounds__(512) void gemm_mfma(const void* __restrict__ Av,
                                                 const unsigned short* __restrict__ BPK,
                                                 const float* __restrict__ biasR,
                                                 const float* __restrict__ wadd,
                                                 void* __restrict__ Cv, int Nout) {
  __shared__ unsigned short abf[4][16 * 512];   // 64KB
  const int tid = threadIdx.x, wave = tid >> 6, lane = tid & 63;
  const int lg = lane >> 4, ln = lane & 15;
  const int wm = wave & 3, wn = wave >> 2;
  const int m0 = blockIdx.x * 64, n0 = blockIdx.y * 128;
  const int Lsrd = lane ^ ((lane >> 3) & 7);

#pragma unroll
  for (int i = 0; i < 8; i++) {
    int g = (i * 512 + tid) * 8;
    int row = g >> 9, col = g & 511;
    ushort8 u;
    if (AF32) {
      const float* A = (const float*)Av;
      float4 v0 = *(const float4*)(A + (size_t)(m0 + row) * 512 + col);
      float4 v1 = *(const float4*)(A + (size_t)(m0 + row) * 512 + col + 4);
      u[0] = f2bf(v0.x); u[1] = f2bf(v0.y); u[2] = f2bf(v0.z); u[3] = f2bf(v0.w);
      u[4] = f2bf(v1.x); u[5] = f2bf(v1.y); u[6] = f2bf(v1.z); u[7] = f2bf(v1.w);
    } else {
      const unsigned short* A = (const unsigned short*)Av;
      u = *(const ushort8*)(A + (size_t)(m0 + row) * 512 + col);
    }
    int strip = row >> 4, m = row & 15;
    int L = (((col >> 3) & 3) << 4) | m;
    int Ls = L ^ ((L >> 3) & 7);
    *(ushort8*)(&abf[strip][((col >> 5) << 9) + (Ls << 3)]) = u;
  }
  __syncthreads();

  const f32x4 zero4 = {0.f, 0.f, 0.f, 0.f};
  f32x4 acc[4] = {zero4, zero4, zero4, zero4};
  const bf16x8* BP = (const bf16x8*)BPK;
  const int ntbase = (n0 >> 4) + wn * 4;
#pragma unroll
  for (int kt = 0; kt < 16; kt++) {
    bf16x8 a = *(const bf16x8*)(&abf[wm][(kt << 9) + (Lsrd << 3)]);
#pragma unroll
    for (int q = 0; q < 4; q++)
      acc[q] = __builtin_amdgcn_mfma_f32_16x16x32_bf16(
          a, BP[(((ntbase + q) * 16 + kt) << 6) + lane], acc[q], 0, 0, 0);
  }

#pragma unroll
  for (int q = 0; q < 4; q++) {
    int col = n0 + ((wn * 4 + q) << 4) + ln;
    float bb = biasR[col];
#pragma unroll
    for (int r = 0; r < 4; r++) {
      int row = m0 + (wm << 4) + (lg << 2) + r;
      float v = acc[q][r] + bb;
      if (wadd) v += wadd[(size_t)row * 512 + col];
      if (OUTBF) ((unsigned short*)Cv)[(size_t)row * Nout + col] = f2bf(v);
      else       ((float*)Cv)[(size_t)row * Nout + col] = v;
    }
  }
}

// ---------------- K5b: transpose+pack F2B (bf16) -> F2T bf16 [t][j<512][m][2(s,g)] ------
__global__ __launch_bounds__(256) void pack_f2t(const unsigned short* __restrict__ F2B,
                                                unsigned short* __restrict__ F2T) {
  __shared__ unsigned short ts_[64][66], tg_[64][66];
  int t = blockIdx.x >> 3, jb = (blockIdx.x & 7) << 6;
  const unsigned short* src = F2B + (size_t)t * 64 * 1024;
  for (int mm = 0; mm < 64; mm += 4) {
    int m = mm + (threadIdx.x >> 6);
    int c = threadIdx.x & 63;
    ts_[m][c] = src[(size_t)m * 1024 + jb + c];
    tg_[m][c] = src[(size_t)m * 1024 + 512 + jb + c];
  }
  __syncthreads();
  unsigned short* dst = F2T + ((size_t)t * 512 + jb) * 128;
  for (int base = threadIdx.x; base < 64 * 128; base += 256) {
    int j = base >> 7, idx = base & 127, m = idx >> 1, sel = idx & 1;
    dst[(size_t)j * 128 + idx] = sel ? tg_[m][j] : ts_[m][j];
  }
}

// ---------------- K6: i8 MFMA recurrence, 1024 thr, 144KB of weights LDS-resident ---------
// Pages 0-1 of Wr and U (128KB) + half of Wr page 2 (nt 0-15, 16KB) pinned in LDS.
// LDS total = 160KB (8 A-h + 8 A-sr + 144 weights) — the full per-CU pool.
// Pages 2(hi-nt)/3-7 of Wr and 2-7 of U streamed from L2 (plain inline loads).
__device__ __forceinline__ int a8off(int m, int j) {
  return ((j >> 6) << 10) + (((((j >> 3) & 3) << 4) + m) << 4) + (((j >> 5) & 1) << 3) + (j & 7);
}
__device__ __forceinline__ float fast_sigmoid(float x) {
  return __builtin_amdgcn_rcpf(1.f + __expf(-x));
}
__device__ __forceinline__ float fast_tanh(float x) {
  x = fminf(15.f, fmaxf(-15.f, x));
  float e = __expf(2.f * x);
  return 1.f - 2.f * __builtin_amdgcn_rcpf(e + 1.f);
}

__global__ __launch_bounds__(1024) void recurrence_i8(
    const unsigned short* __restrict__ F2T,
    const signed char* __restrict__ WrPK8,
    const signed char* __restrict__ UPK8,
    const float* __restrict__ wscWr,
    const float* __restrict__ wscU,
    const float* __restrict__ gru_init,
    float* __restrict__ hout) {
  __shared__ long long hq8[1024];     // 8KB i8 A-buffer (h)
  __shared__ long long srq8[1024];    // 8KB i8 A-buffer (sr)
  __shared__ long long wldsWr[8192];  // 64KB: Wr pages 0-1, chunk idx (nt*2+p)*64 + l
  __shared__ long long wldsU[8192];   // 64KB: U  pages 0-1
  __shared__ long long wldsWr2[2048]; // 16KB: Wr page 2 for nt 0-15, chunk idx nt*64 + l
  signed char* hqc  = (signed char*)hq8;
  signed char* srqc = (signed char*)srq8;
  const int tid  = threadIdx.x;
  const int wave = tid >> 6;        // 0..15
  const int lane = tid & 63;
  const int lg = lane >> 4;
  const int ln = lane & 15;
  const int b0 = blockIdx.x * 16;

  const signed char* wrq0 = WrPK8 + (size_t)(wave * 2 + 0) * 8192 + lane * 16;
  const signed char* wrq1 = WrPK8 + (size_t)(wave * 2 + 1) * 8192 + lane * 16;
  const signed char* uq0  = UPK8  + (size_t)(wave * 2 + 0) * 8192 + lane * 16;
  const signed char* uq1  = UPK8  + (size_t)(wave * 2 + 1) * 8192 + lane * 16;

  // LDS-resident page pointers (16B-chunk index = (nt*2+p)*64 + lane)
  const ll2* wl0 = (const ll2*)wldsWr + ((wave * 2 + 0) * 2) * 64 + lane;
  const ll2* wl1 = (const ll2*)wldsWr + ((wave * 2 + 1) * 2) * 64 + lane;
  const ll2* ul0 = (const ll2*)wldsU  + ((wave * 2 + 0) * 2) * 64 + lane;
  const ll2* ul1 = (const ll2*)wldsU  + ((wave * 2 + 1) * 2) * 64 + lane;
  // Wr page-2 LDS pointers (valid for wave < 8, nt = wave*2+q < 16)
  const ll2* w2l0 = (const ll2*)wldsWr2 + (wave * 2 + 0) * 64 + lane;
  const ll2* w2l1 = (const ll2*)wldsWr2 + (wave * 2 + 1) * 64 + lane;

  // ---- stage resident weight pages to LDS (once) ----
  {
    const ll2* s1 = (const ll2*)WrPK8;
    const ll2* s2 = (const ll2*)UPK8;
    ll2* d1 = (ll2*)wldsWr;
    ll2* d2 = (ll2*)wldsU;
#pragma unroll
    for (int c = 0; c < 4; c++) {
      int i = tid + c * 1024;                 // LDS 16B-chunk 0..4095
      int l = i & 63, p = (i >> 6) & 1, nt = i >> 7;
      int g = (nt * 8 + p) * 64 + l;          // global 16B-chunk
      d1[i] = s1[g];
      d2[i] = s2[g];
    }
    // Wr page 2, nt 0..15: 1024 chunks
    ll2* d3 = (ll2*)wldsWr2;
    int i = tid;
    if (i < 1024) {
      int l = i & 63, nt = i >> 6;
      int g = (nt * 8 + 2) * 64 + l;
      d3[i] = s1[g];
    }
  }

  float wscWrR[2], wscUR[2];
#pragma unroll
  for (int q = 0; q < 2; q++) {
    int j = ((wave * 2 + q) << 4) + ln;
    wscWrR[q] = wscWr[j];
    wscUR[q]  = wscU[j];
  }

  // ---- init h: fp32 master in regs, i8 copy in LDS ----
  float hreg[2][4];
  float hdq = 2.0f / 127.0f;
  {
    float hqi = 127.0f / 2.0f;
#pragma unroll
    for (int q = 0; q < 2; q++) {
      int j = ((wave * 2 + q) << 4) + ln;
#pragma unroll
      for (int r = 0; r < 4; r++) {
        int m = (lg << 2) + r;
        float v = gru_init[(b0 + m) * D + j];
        hreg[q][r] = v;
        int qv = __float2int_rn(v * hqi);
        qv = qv > 127 ? 127 : (qv < -127 ? -127 : qv);
        hqc[a8off(m, j)] = (signed char)qv;
      }
    }
  }
  __syncthreads();

  const i32x4 z4 = {0, 0, 0, 0};
#pragma unroll 1
  for (int t = 0; t < TS; t++) {
    const unsigned short* f2t = F2T + (size_t)t * (512 * 128);
    float sreg[2][4], greg[2][4];
#pragma unroll
    for (int q = 0; q < 2; q++) {
      int j = ((wave * 2 + q) << 4) + ln;
      ushort8 v = *(const ushort8*)(f2t + (size_t)j * 128 + ((b0 + (lg << 2)) << 1));
#pragma unroll
      for (int r = 0; r < 4; r++) {
        sreg[q][r] = bf2f(v[2 * r]);
        greg[q][r] = bf2f(v[2 * r + 1]);
      }
    }
    // ---- matvec1: pages 0-1 from LDS, page 2 from LDS (waves 0-7) / L2, 3-7 from L2 ----
    i32x4 c1[2] = {z4, z4};
#pragma unroll
    for (int p = 0; p < 2; p++) {
      ll2 a2 = *(const ll2*)(hqc + (p << 10) + (lane << 4));
      ll2 w0 = wl0[p << 6];
      ll2 w1 = wl1[p << 6];
      c1[0] = __builtin_amdgcn_mfma_i32_16x16x32_i8(a2[0], w0[0], c1[0], 0, 0, 0);
      c1[0] = __builtin_amdgcn_mfma_i32_16x16x32_i8(a2[1], w0[1], c1[0], 0, 0, 0);
      c1[1] = __builtin_amdgcn_mfma_i32_16x16x32_i8(a2[0], w1[0], c1[1], 0, 0, 0);
      c1[1] = __builtin_amdgcn_mfma_i32_16x16x32_i8(a2[1], w1[1], c1[1], 0, 0, 0);
    }
    {
      ll2 a2 = *(const ll2*)(hqc + (2 << 10) + (lane << 4));
      ll2 w0, w1;
      if (wave < 8) { w0 = w2l0[0]; w1 = w2l1[0]; }
      else {
        w0 = *(const ll2*)(wrq0 + (2 << 10));
        w1 = *(const ll2*)(wrq1 + (2 << 10));
      }
      c1[0] = __builtin_amdgcn_mfma_i32_16x16x32_i8(a2[0], w0[0], c1[0], 0, 0, 0);
      c1[0] = __builtin_amdgcn_mfma_i32_16x16x32_i8(a2[1], w0[1], c1[0], 0, 0, 0);
      c1[1] = __builtin_amdgcn_mfma_i32_16x16x32_i8(a2[0], w1[0], c1[1], 0, 0, 0);
      c1[1] = __builtin_amdgcn_mfma_i32_16x16x32_i8(a2[1], w1[1], c1[1], 0, 0, 0);
    }
#pragma unroll
    for (int p = 3; p < 8; p++) {
      ll2 a2 = *(const ll2*)(hqc + (p << 10) + (lane << 4));
      ll2 w0 = *(const ll2*)(wrq0 + (p << 10));
      ll2 w1 = *(const ll2*)(wrq1 + (p << 10));
      c1[0] = __builtin_amdgcn_mfma_i32_16x16x32_i8(a2[0], w0[0], c1[0], 0, 0, 0);
      c1[0] = __builtin_amdgcn_mfma_i32_16x16x32_i8(a2[1], w0[1], c1[0], 0, 0, 0);
      c1[1] = __builtin_amdgcn_mfma_i32_16x16x32_i8(a2[0], w1[0], c1[1], 0, 0, 0);
      c1[1] = __builtin_amdgcn_mfma_i32_16x16x32_i8(a2[1], w1[1], c1[1], 0, 0, 0);
    }
    // ---- epilogue 1: sr = s * sigmoid(dequant(c1) + g), quantize to i8 (+-8 range) ----
#pragma unroll
    for (int q = 0; q < 2; q++) {
      int j = ((wave * 2 + q) << 4) + ln;
      float d1 = hdq * wscWrR[q];
#pragma unroll
      for (int r = 0; r < 4; r++) {
        int m = (lg << 2) + r;
        float c1f = (float)c1[q][r] * d1;
        float rr = fast_sigmoid(c1f + greg[q][r]);
        float sr = sreg[q][r] * rr;
        int qv = __float2int_rn(sr * (127.0f / 8.0f));
        qv = qv > 127 ? 127 : (qv < -127 ? -127 : qv);
        srqc[a8off(m, j)] = (signed char)qv;
      }
    }
    __syncthreads();
    // ---- matvec2: pages 0-1 from LDS, 2-7 from L2 ----
    i32x4 c2[2] = {z4, z4};
#pragma unroll
    for (int p = 0; p < 2; p++) {
      ll2 a2 = *(const ll2*)(srqc + (p << 10) + (lane << 4));
      ll2 w0 = ul0[p << 6];
      ll2 w1 = ul1[p << 6];
      c2[0] = __builtin_amdgcn_mfma_i32_16x16x32_i8(a2[0], w0[0], c2[0], 0, 0, 0);
      c2[0] = __builtin_amdgcn_mfma_i32_16x16x32_i8(a2[1], w0[1], c2[0], 0, 0, 0);
      c2[1] = __builtin_amdgcn_mfma_i32_16x16x32_i8(a2[0], w1[0], c2[1], 0, 0, 0);
      c2[1] = __builtin_amdgcn_mfma_i32_16x16x32_i8(a2[1], w1[1], c2[1], 0, 0, 0);
    }
#pragma unroll
    for (int p = 2; p < 8; p++) {
      ll2 a2 = *(const ll2*)(srqc + (p << 10) + (lane << 4));
      ll2 w0 = *(const ll2*)(uq0 + (p << 10));
      ll2 w1 = *(const ll2*)(uq1 + (p << 10));
      c2[0] = __builtin_amdgcn_mfma_i32_16x16x32_i8(a2[0], w0[0], c2[0], 0, 0, 0);
      c2[0] = __builtin_amdgcn_mfma_i32_16x16x32_i8(a2[1], w0[1], c2[0], 0, 0, 0);
      c2[1] = __builtin_amdgcn_mfma_i32_16x16x32_i8(a2[0], w1[0], c2[1], 0, 0, 0);
      c2[1] = __builtin_amdgcn_mfma_i32_16x16x32_i8(a2[1], w1[1], c2[1], 0, 0, 0);
    }
    // ---- epilogue 2: h += 1 + tanh(dequant(c2) + s); write hout + quantized h ----
    {
      float hbn = 2.0f * (float)(t + 1) + 2.0f;
      float hqin = 127.0f / hbn;
#pragma unroll
      for (int q = 0; q < 2; q++) {
        int j = ((wave * 2 + q) << 4) + ln;
        float d2 = (8.0f / 127.0f) * wscUR[q];
#pragma unroll
        for (int r = 0; r < 4; r++) {
          int m = (lg << 2) + r;
          float c2f = (float)c2[q][r] * d2;
          float hn = hreg[q][r] + 1.f + fast_tanh(c2f + sreg[q][r]);
          hreg[q][r] = hn;
          hout[((size_t)t * MB + (b0 + m)) * D + j] = hn;
          int qv = __float2int_rn(hn * hqin);
          qv = qv > 127 ? 127 : (qv < -127 ? -127 : qv);
          hqc[a8off(m, j)] = (signed char)qv;
        }
      }
      hdq = hbn * (1.0f / 127.0f);
    }
    __syncthreads();
  }
}

extern "C" void kernel_launch(void* const* d_in, const int* in_sizes, int n_in,
                              void* d_out, int out_size, void* d_ws, size_t ws_size,
                              hipStream_t stream) {
  const float* c_inp    = (const float*)d_in[0];
  const float* inp      = (const float*)d_in[1];
  const float* gru_init = (const float*)d_in[2];
  const float* att_init = (const float*)d_in[3];
  const float* Wa   = (const float*)d_in[4];
  const float* ba   = (const float*)d_in[5];
  const float* Wb   = (const float*)d_in[6];
  const float* bb   = (const float*)d_in[7];
  const float* Wk   = (const float*)d_in[8];
  const float* bk   = (const float*)d_in[9];
  const float* Wif  = (const float*)d_in[10];
  const float* bif  = (const float*)d_in[11];
  const float* Wfork= (const float*)d_in[12];
  const float* bfork= (const float*)d_in[13];
  const float* Wur  = (const float*)d_in[14];
  const float* U    = (const float*)d_in[15];

  float* out = (float*)d_out;
  float* hid  = out;
  float* attk = out + ATTK_OFF;
  float* attw = out + ATTW_OFF;

  char* ws = (char*)d_ws;
  signed char* WrPK8 = (signed char*)(ws + WS_WRPK8);
  signed char* UPK8  = (signed char*)(ws + WS_UPK8);
  float* wscWr = (float*)(ws + WS_WSC);
  float* wscU  = (float*)(ws + WS_WSC + 2048);
  float* biasR1 = (float*)(ws + WS_BIAS1);
  float* biasR2 = (float*)(ws + WS_BIAS2);
  float* alpha = (float*)(ws + WS_ALPHA);
  float* beta  = (float*)(ws + WS_BETA);
  float* kinc  = (float*)(ws + WS_KINC);
  unsigned short* XB     = (unsigned short*)(ws + WS_X);
  unsigned short* WIFPK  = (unsigned short*)(ws + WS_WIFPK);
  unsigned short* WFORKPK= (unsigned short*)(ws + WS_WFORKPK);
  unsigned short* F2T    = (unsigned short*)(ws + WS_F2T);
  unsigned short* F2B    = (unsigned short*)(ws + WS_F2);

  hipLaunchKernelGGL(col_scales, dim3(2), dim3(256), 0, stream, Wur, U, wscWr, wscU);
  hipLaunchKernelGGL(pack_weights_i8, dim3(1024), dim3(256), 0, stream,
                     Wur, U, wscWr, wscU, WrPK8, UPK8);
  hipLaunchKernelGGL(pack_gemm_w, dim3(512 * 512 / 256), dim3(256), 0, stream,
                     Wif, bif, WIFPK, biasR1, 512, 512, 0);
  hipLaunchKernelGGL(pack_gemm_w, dim3(1024 * 512 / 256), dim3(256), 0, stream,
                     Wfork, bfork, WFORKPK, biasR2, 1536, 1024, 1);
  hipLaunchKernelGGL(abk_kernel, dim3(TS * MB / ABK_ROWS), dim3(64), 0, stream,
                     inp, Wa, ba, Wb, bb, Wk, bk, alpha, beta, kinc);
  hipLaunchKernelGGL(cumsum_kernel, dim3((MB * KMIX + 255) / 256), dim3(256), 0, stream,
                     att_init, kinc, attk);
  hipLaunchKernelGGL(phi_w_kernel, dim3(MB * (TS / WT)), dim3(512), 0, stream,
                     c_inp, alpha, beta, attk, attw);
  hipLaunchKernelGGL((gemm_mfma<1, 1>), dim3(TS * MB / 64, 512 / 128), dim3(512), 0, stream,
                     inp, WIFPK, biasR1, attw, XB, 512);
  hipLaunchKernelGGL((gemm_mfma<0, 1>), dim3(TS * MB / 64, 1024 / 128), dim3(512), 0, stream,
                     XB, WFORKPK, biasR2, (const float*)nullptr, F2B, 1024);
  hipLaunchKernelGGL(pack_f2t, dim3(256 * 8), dim3(256), 0, stream, F2B, F2T);
  hipLaunchKernelGGL(recurrence_i8, dim3(4), dim3(1024), 0, stream,
                     F2T, WrPK8, UPK8, wscWr, wscU, gru_init, hid);
}